// Round 1
// 620.560 us; speedup vs baseline: 1.1414x; 1.1414x over previous
//
#include <hip/hip_runtime.h>

#define N_NODES   100000
#define N_EDGES   3200000
#define N_FEAT    128
#define HIDDEN    16
#define N_CLASSES 10
#define N_GRAPHS  64

#define SCAN_B    391          // ceil(N_NODES/256)

// Workspace layout (4-byte units):
//   cnt    : [0,       100000)   int, zeroed
//   dinv   : [100000,  200000)   float
//   off    : [200000,  300016)   int (100001 used)
//   cursor : [300016,  400016)   int
//   bsum   : [400016,  400416)   int (391 used)
//   bofs   : [400416,  400816)   int (391 used)
//   srcs   : [400816, 3600816)   int (CSR by dst)
//   h1p    : [3600816, 5200816)  float [N][16]  (x@W1)*dinv[row]
//   h2p    : [5200816, 6800816)  float [N][16]  (relu(a1)@W2)*dinv[row], c>=10 zero
// total ~27.2 MB

__global__ __launch_bounds__(256) void k_count(const int* __restrict__ dst,
                                               int* __restrict__ cnt) {
    int i = blockIdx.x * 256 + threadIdx.x;
    if (i < N_EDGES) atomicAdd(&cnt[dst[i]], 1);
}

__global__ __launch_bounds__(256) void k_scanA(const int* __restrict__ cnt,
                                               int* __restrict__ bsum) {
    __shared__ int s[256];
    int t = threadIdx.x;
    int i = blockIdx.x * 256 + t;
    s[t] = (i < N_NODES) ? cnt[i] : 0;
    __syncthreads();
    for (int o = 128; o > 0; o >>= 1) {
        if (t < o) s[t] += s[t + o];
        __syncthreads();
    }
    if (t == 0) bsum[blockIdx.x] = s[0];
}

__global__ __launch_bounds__(512) void k_scanB(const int* __restrict__ bsum,
                                               int* __restrict__ bofs) {
    __shared__ int s[512];
    int t = threadIdx.x;
    int v = (t < SCAN_B) ? bsum[t] : 0;
    s[t] = v;
    __syncthreads();
    for (int o = 1; o < 512; o <<= 1) {
        int a = (t >= o) ? s[t - o] : 0;
        __syncthreads();
        s[t] += a;
        __syncthreads();
    }
    if (t < SCAN_B) bofs[t] = s[t] - v;   // exclusive
}

__global__ __launch_bounds__(256) void k_scanC(const int* __restrict__ cnt,
                                               const int* __restrict__ bofs,
                                               int* __restrict__ off,
                                               int* __restrict__ cursor,
                                               float* __restrict__ dinv) {
    __shared__ int s[256];
    int t = threadIdx.x;
    int i = blockIdx.x * 256 + t;
    int v = (i < N_NODES) ? cnt[i] : 0;
    s[t] = v;
    __syncthreads();
    for (int o = 1; o < 256; o <<= 1) {
        int a = (t >= o) ? s[t - o] : 0;
        __syncthreads();
        s[t] += a;
        __syncthreads();
    }
    int excl = s[t] - v + bofs[blockIdx.x];
    if (i < N_NODES) {
        off[i]    = excl;
        cursor[i] = excl;
        dinv[i]   = rsqrtf((float)v + 1.0f);
    }
    if (i == N_NODES - 1) off[N_NODES] = excl + v;
}

__global__ __launch_bounds__(256) void k_fill(const int* __restrict__ src,
                                              const int* __restrict__ dst,
                                              int* __restrict__ cursor,
                                              int* __restrict__ srcs) {
    int e = blockIdx.x * 256 + threadIdx.x;
    if (e < N_EDGES) {
        int d = dst[e];
        int p = atomicAdd(&cursor[d], 1);
        srcs[p] = src[e];
    }
}

// 16 nodes per block: h1p[n][c] = (x[n] @ W1)[c] * dinv[n]
__global__ __launch_bounds__(256) void k_gemm1(const float* __restrict__ x,
                                               const float* __restrict__ W1,
                                               const float* __restrict__ dinv,
                                               float* __restrict__ h1p) {
    __shared__ float w[N_FEAT * HIDDEN];   // 8 KB
    __shared__ float xs[16 * N_FEAT];      // 8 KB
    __shared__ float ds[16];
    int tid  = threadIdx.x;
    int base = blockIdx.x * 16;
    if (tid < 16) ds[tid] = dinv[base + tid];
    const float4* w4 = (const float4*)W1;
    float4*       wd = (float4*)w;
    wd[tid]       = w4[tid];
    wd[256 + tid] = w4[256 + tid];
    const float4* x4 = (const float4*)(x + (long long)base * N_FEAT);
    float4*       xd = (float4*)xs;
    xd[tid]       = x4[tid];
    xd[256 + tid] = x4[256 + tid];
    __syncthreads();
    int n = tid >> 4, c = tid & 15;
    const float* xr = &xs[n * N_FEAT];
    float acc = 0.f;
#pragma unroll
    for (int k = 0; k < N_FEAT; ++k) acc += xr[k] * w[k * HIDDEN + c];
    h1p[(base + n) * HIDDEN + c] = acc * ds[n];
}

// Fused: CSR gather of layer-1 aggregation + bias + ReLU + (@W2) + dinv scale.
// 16 lanes (channels) per node, 16 nodes per block.
// h2p[n][c] = dinv[n] * (relu(dinv[n]*(sum_in h1p[s] + h1p[n]) + b1) @ W2)[c], c<10; else 0
__global__ __launch_bounds__(256) void k_agg1(const int* __restrict__ off,
                                              const int* __restrict__ srcs,
                                              const float* __restrict__ dinv,
                                              const float* __restrict__ h1p,
                                              const float* __restrict__ b1,
                                              const float* __restrict__ W2,
                                              float* __restrict__ h2p) {
    __shared__ float r_s[16][17];
    __shared__ float w2s[HIDDEN * N_CLASSES];
    int tid = threadIdx.x;
    if (tid < HIDDEN * N_CLASSES) w2s[tid] = W2[tid];
    int nl = tid >> 4, c = tid & 15;
    int n  = blockIdx.x * 16 + nl;
    int beg = off[n], end = off[n + 1];
    float a0 = h1p[n * 16 + c];            // self-loop
    float a1 = 0.f, a2 = 0.f, a3 = 0.f;
    int j = beg;
    for (; j + 3 < end; j += 4) {
        int s0 = srcs[j], s1 = srcs[j + 1], s2 = srcs[j + 2], s3 = srcs[j + 3];
        a0 += h1p[s0 * 16 + c];
        a1 += h1p[s1 * 16 + c];
        a2 += h1p[s2 * 16 + c];
        a3 += h1p[s3 * 16 + c];
    }
    for (; j < end; ++j) a0 += h1p[srcs[j] * 16 + c];
    float acc = (a0 + a1) + (a2 + a3);
    float dn  = dinv[n];
    r_s[nl][c] = fmaxf(dn * acc + b1[c], 0.f);
    __syncthreads();
    if (c < N_CLASSES) {
        float o = 0.f;
#pragma unroll
        for (int k = 0; k < HIDDEN; ++k) o += r_s[nl][k] * w2s[k * N_CLASSES + c];
        h2p[n * 16 + c] = dn * o;
    } else {
        h2p[n * 16 + c] = 0.f;
    }
}

// CSR gather of layer-2 aggregation; writes final per-node logits-contribution
// out2[n][c] = dinv[n] * (sum_in h2p[s] + h2p[n]),  c>=10 stays 0.
__global__ __launch_bounds__(256) void k_agg2(const int* __restrict__ off,
                                              const int* __restrict__ srcs,
                                              const float* __restrict__ dinv,
                                              const float* __restrict__ h2p,
                                              float* __restrict__ out2) {
    int tid = threadIdx.x;
    int nl = tid >> 4, c = tid & 15;
    int n  = blockIdx.x * 16 + nl;
    int beg = off[n], end = off[n + 1];
    float a0 = h2p[n * 16 + c];            // self-loop
    float a1 = 0.f, a2 = 0.f, a3 = 0.f;
    int j = beg;
    for (; j + 3 < end; j += 4) {
        int s0 = srcs[j], s1 = srcs[j + 1], s2 = srcs[j + 2], s3 = srcs[j + 3];
        a0 += h2p[s0 * 16 + c];
        a1 += h2p[s1 * 16 + c];
        a2 += h2p[s2 * 16 + c];
        a3 += h2p[s3 * 16 + c];
    }
    for (; j < end; ++j) a0 += h2p[srcs[j] * 16 + c];
    out2[n * 16 + c] = dinv[n] * ((a0 + a1) + (a2 + a3));
}

// one block per graph; batch sorted -> binary search the node range,
// block-reduce sums, mean + b2, log_softmax straight to d_out.
__global__ __launch_bounds__(256) void k_pool(const float* __restrict__ out2,
                                              const float* __restrict__ b2,
                                              const int* __restrict__ batch,
                                              float* __restrict__ out) {
    __shared__ float red[N_CLASSES][256];
    int g = blockIdx.x, tid = threadIdx.x;
    int lo = 0, hi = N_NODES;
    while (lo < hi) { int m = (lo + hi) >> 1; if (batch[m] < g) lo = m + 1; else hi = m; }
    int start = lo;
    lo = 0; hi = N_NODES;
    while (lo < hi) { int m = (lo + hi) >> 1; if (batch[m] < g + 1) lo = m + 1; else hi = m; }
    int end = lo;

    float sum[N_CLASSES];
#pragma unroll
    for (int j = 0; j < N_CLASSES; ++j) sum[j] = 0.f;
    for (int i = start + tid; i < end; i += 256) {
        const float* r = &out2[(long long)i * 16];
#pragma unroll
        for (int j = 0; j < N_CLASSES; ++j) sum[j] += r[j];
    }
#pragma unroll
    for (int j = 0; j < N_CLASSES; ++j) red[j][tid] = sum[j];
    __syncthreads();
    for (int s = 128; s > 0; s >>= 1) {
        if (tid < s) {
#pragma unroll
            for (int j = 0; j < N_CLASSES; ++j) red[j][tid] += red[j][tid + s];
        }
        __syncthreads();
    }
    if (tid == 0) {
        int cnt = end - start;
        float v[N_CLASSES];
        if (cnt > 0) {
            float inv = 1.f / (float)cnt;
#pragma unroll
            for (int j = 0; j < N_CLASSES; ++j) v[j] = red[j][0] * inv + b2[j];
        } else {
#pragma unroll
            for (int j = 0; j < N_CLASSES; ++j) v[j] = 0.f;
        }
        float m = v[0];
#pragma unroll
        for (int j = 1; j < N_CLASSES; ++j) m = fmaxf(m, v[j]);
        float l = 0.f;
#pragma unroll
        for (int j = 0; j < N_CLASSES; ++j) l += expf(v[j] - m);
        l = logf(l);
#pragma unroll
        for (int j = 0; j < N_CLASSES; ++j) out[g * N_CLASSES + j] = v[j] - m - l;
    }
}

extern "C" void kernel_launch(void* const* d_in, const int* in_sizes, int n_in,
                              void* d_out, int out_size, void* d_ws, size_t ws_size,
                              hipStream_t stream) {
    const float* x     = (const float*)d_in[0];
    const int*   edge  = (const int*)d_in[1];   // [2, E]
    const int*   batch = (const int*)d_in[2];
    const float* W1    = (const float*)d_in[3];
    const float* b1    = (const float*)d_in[4];
    const float* W2    = (const float*)d_in[5];
    const float* b2    = (const float*)d_in[6];
    float* out = (float*)d_out;
    float* ws  = (float*)d_ws;

    int*   cnt    = (int*)ws;                 // [0, 100000)
    float* dinv   = ws + 100000;              // [100000, 200000)
    int*   off    = (int*)(ws + 200000);      // 100001 used
    int*   cursor = (int*)(ws + 300016);
    int*   bsum   = (int*)(ws + 400016);
    int*   bofs   = (int*)(ws + 400416);
    int*   srcs   = (int*)(ws + 400816);      // 3.2M
    float* h1p    = ws + 3600816;             // [N][16]
    float* h2p    = ws + 5200816;             // [N][16]
    float* out2   = h1p;                      // h1p dead after k_agg1

    const int* srcp = edge;
    const int* dstp = edge + N_EDGES;

    hipMemsetAsync(cnt, 0, (size_t)N_NODES * sizeof(int), stream);

    k_count<<<N_EDGES / 256, 256, 0, stream>>>(dstp, cnt);
    k_scanA<<<SCAN_B, 256, 0, stream>>>(cnt, bsum);
    k_scanB<<<1, 512, 0, stream>>>(bsum, bofs);
    k_scanC<<<SCAN_B, 256, 0, stream>>>(cnt, bofs, off, cursor, dinv);
    k_gemm1<<<N_NODES / 16, 256, 0, stream>>>(x, W1, dinv, h1p);
    k_fill<<<N_EDGES / 256, 256, 0, stream>>>(srcp, dstp, cursor, srcs);
    k_agg1<<<N_NODES / 16, 256, 0, stream>>>(off, srcs, dinv, h1p, b1, W2, h2p);
    k_agg2<<<N_NODES / 16, 256, 0, stream>>>(off, srcs, dinv, h2p, out2);
    k_pool<<<N_GRAPHS, 256, 0, stream>>>(out2, b2, batch, out);
}

// Round 2
// 298.849 us; speedup vs baseline: 2.3701x; 2.0765x over previous
//
#include <hip/hip_runtime.h>

#define N_NODES   100000
#define N_EDGES   3200000
#define N_FEAT    128
#define HIDDEN    16
#define N_CLASSES 10
#define N_GRAPHS  64

#define NBUCK     391          // ceil(N_NODES/256), bucket = dst >> 8
#define CAP       9216         // staging capacity per bucket (mean 8192, +11 sigma)
#define BINA_EPB  4096         // edges per block in k_binA
#define BINA_BLOCKS ((N_EDGES + BINA_EPB - 1) / BINA_EPB)   // 782

// Workspace layout (4-byte units):
//   gcur  : [0,        512)       int, per-bucket staging cursor
//   bbase : [512,      1024)      int, per-bucket CSR base
//   dinv  : [1024,     101024)    float
//   off   : [101024,   201025)    int (100001 used), pad to 201056
//   srcs  : [201056,   3401056)   int, CSR by dst
//   stage : [3401056,  7004512)   int, 391*9216 packed (src<<8 | dst&255)
//   h1p   : [3401056,  5001056)   float [N][16]  (overlays stage; stage dead by then)
//   h2p   : [5001056,  6601056)   float [N][16]
// total 7,004,512 floats = 28.0 MB

__global__ __launch_bounds__(512) void k_ginit(int* __restrict__ gcur) {
    int t = threadIdx.x;
    if (t < NBUCK) gcur[t] = t * CAP;
}

// Bin edges by dst>>8 into per-bucket staging. Per block: LDS histogram ->
// one global atomic per bucket to reserve a contiguous range -> LDS-cursor
// scatter. Writes per (block,bucket) are contiguous -> lines fill in L2.
__global__ __launch_bounds__(256) void k_binA(const int* __restrict__ src,
                                              const int* __restrict__ dst,
                                              int* __restrict__ gcur,
                                              int* __restrict__ stage) {
    __shared__ int hist[NBUCK];
    __shared__ int curb[NBUCK];
    int tid = threadIdx.x;
    long long base = (long long)blockIdx.x * BINA_EPB;
    for (int t = tid; t < NBUCK; t += 256) hist[t] = 0;
    __syncthreads();
    int se[16], de[16];
#pragma unroll
    for (int i = 0; i < 16; ++i) {
        long long e = base + i * 256 + tid;
        if (e < N_EDGES) {
            se[i] = src[e];
            de[i] = dst[e];
            atomicAdd(&hist[de[i] >> 8], 1);
        } else {
            de[i] = -1;
        }
    }
    __syncthreads();
    for (int t = tid; t < NBUCK; t += 256) {
        int h = hist[t];
        curb[t] = h ? atomicAdd(&gcur[t], h) : 0;
    }
    __syncthreads();
#pragma unroll
    for (int i = 0; i < 16; ++i) {
        if (de[i] >= 0) {
            int b = de[i] >> 8;
            int p = atomicAdd(&curb[b], 1);
            stage[p] = (se[i] << 8) | (de[i] & 255);
        }
    }
}

// Exclusive scan of bucket counts -> per-bucket CSR base.
__global__ __launch_bounds__(512) void k_bscan(const int* __restrict__ gcur,
                                               int* __restrict__ bbase,
                                               int* __restrict__ off) {
    __shared__ int s[512];
    int t = threadIdx.x;
    int c = (t < NBUCK) ? (gcur[t] - t * CAP) : 0;
    s[t] = c;
    __syncthreads();
    for (int o = 1; o < 512; o <<= 1) {
        int a = (t >= o) ? s[t - o] : 0;
        __syncthreads();
        s[t] += a;
        __syncthreads();
    }
    if (t < NBUCK) bbase[t] = s[t] - c;
    if (t == 0) off[N_NODES] = N_EDGES;
}

// One block per bucket: per-node histogram + scan -> off/dinv, then place
// each staged edge at its final CSR slot (all writes within the bucket's
// ~36 KB CSR window -> L2-resident, lines fill).
__global__ __launch_bounds__(256) void k_binB(const int* __restrict__ gcur,
                                              const int* __restrict__ bbase,
                                              const int* __restrict__ stage,
                                              int* __restrict__ off,
                                              float* __restrict__ dinv,
                                              int* __restrict__ srcs) {
    __shared__ int hist[256];
    __shared__ int excl[256];
    int b = blockIdx.x, t = threadIdx.x;
    int cnt   = gcur[b] - b * CAP;
    int sbase = b * CAP;
    int cbase = bbase[b];
    hist[t] = 0;
    __syncthreads();
    for (int i = t; i < cnt; i += 256) {
        int v = stage[sbase + i];
        atomicAdd(&hist[v & 255], 1);
    }
    __syncthreads();
    int c = hist[t];
    excl[t] = c;
    __syncthreads();
    for (int o = 1; o < 256; o <<= 1) {
        int a = (t >= o) ? excl[t - o] : 0;
        __syncthreads();
        excl[t] += a;
        __syncthreads();
    }
    int ex = excl[t] - c;
    int node = b * 256 + t;
    if (node < N_NODES) {
        off[node]  = cbase + ex;
        dinv[node] = rsqrtf((float)c + 1.0f);
    }
    __syncthreads();
    hist[t] = ex;          // reuse as per-node cursor
    __syncthreads();
    for (int i = t; i < cnt; i += 256) {
        int v = stage[sbase + i];
        int p = cbase + atomicAdd(&hist[v & 255], 1);
        srcs[p] = v >> 8;
    }
}

// 16 nodes per block: h1p[n][c] = (x[n] @ W1)[c] * dinv[n]
__global__ __launch_bounds__(256) void k_gemm1(const float* __restrict__ x,
                                               const float* __restrict__ W1,
                                               const float* __restrict__ dinv,
                                               float* __restrict__ h1p) {
    __shared__ float w[N_FEAT * HIDDEN];   // 8 KB
    __shared__ float xs[16 * N_FEAT];      // 8 KB
    __shared__ float ds[16];
    int tid  = threadIdx.x;
    int base = blockIdx.x * 16;
    if (tid < 16) ds[tid] = dinv[base + tid];
    const float4* w4 = (const float4*)W1;
    float4*       wd = (float4*)w;
    wd[tid]       = w4[tid];
    wd[256 + tid] = w4[256 + tid];
    const float4* x4 = (const float4*)(x + (long long)base * N_FEAT);
    float4*       xd = (float4*)xs;
    xd[tid]       = x4[tid];
    xd[256 + tid] = x4[256 + tid];
    __syncthreads();
    int n = tid >> 4, c = tid & 15;
    const float* xr = &xs[n * N_FEAT];
    float acc = 0.f;
#pragma unroll
    for (int k = 0; k < N_FEAT; ++k) acc += xr[k] * w[k * HIDDEN + c];
    h1p[(base + n) * HIDDEN + c] = acc * ds[n];
}

// Fused: CSR gather of layer-1 aggregation + bias + ReLU + (@W2) + dinv scale.
__global__ __launch_bounds__(256) void k_agg1(const int* __restrict__ off,
                                              const int* __restrict__ srcs,
                                              const float* __restrict__ dinv,
                                              const float* __restrict__ h1p,
                                              const float* __restrict__ b1,
                                              const float* __restrict__ W2,
                                              float* __restrict__ h2p) {
    __shared__ float r_s[16][17];
    __shared__ float w2s[HIDDEN * N_CLASSES];
    int tid = threadIdx.x;
    if (tid < HIDDEN * N_CLASSES) w2s[tid] = W2[tid];
    int nl = tid >> 4, c = tid & 15;
    int n  = blockIdx.x * 16 + nl;
    int beg = off[n], end = off[n + 1];
    float a0 = h1p[n * 16 + c];            // self-loop
    float a1 = 0.f, a2 = 0.f, a3 = 0.f;
    int j = beg;
    for (; j + 3 < end; j += 4) {
        int s0 = srcs[j], s1 = srcs[j + 1], s2 = srcs[j + 2], s3 = srcs[j + 3];
        a0 += h1p[s0 * 16 + c];
        a1 += h1p[s1 * 16 + c];
        a2 += h1p[s2 * 16 + c];
        a3 += h1p[s3 * 16 + c];
    }
    for (; j < end; ++j) a0 += h1p[srcs[j] * 16 + c];
    float acc = (a0 + a1) + (a2 + a3);
    float dn  = dinv[n];
    r_s[nl][c] = fmaxf(dn * acc + b1[c], 0.f);
    __syncthreads();
    if (c < N_CLASSES) {
        float o = 0.f;
#pragma unroll
        for (int k = 0; k < HIDDEN; ++k) o += r_s[nl][k] * w2s[k * N_CLASSES + c];
        h2p[n * 16 + c] = dn * o;
    } else {
        h2p[n * 16 + c] = 0.f;
    }
}

// CSR gather of layer-2 aggregation.
__global__ __launch_bounds__(256) void k_agg2(const int* __restrict__ off,
                                              const int* __restrict__ srcs,
                                              const float* __restrict__ dinv,
                                              const float* __restrict__ h2p,
                                              float* __restrict__ out2) {
    int tid = threadIdx.x;
    int nl = tid >> 4, c = tid & 15;
    int n  = blockIdx.x * 16 + nl;
    int beg = off[n], end = off[n + 1];
    float a0 = h2p[n * 16 + c];            // self-loop
    float a1 = 0.f, a2 = 0.f, a3 = 0.f;
    int j = beg;
    for (; j + 3 < end; j += 4) {
        int s0 = srcs[j], s1 = srcs[j + 1], s2 = srcs[j + 2], s3 = srcs[j + 3];
        a0 += h2p[s0 * 16 + c];
        a1 += h2p[s1 * 16 + c];
        a2 += h2p[s2 * 16 + c];
        a3 += h2p[s3 * 16 + c];
    }
    for (; j < end; ++j) a0 += h2p[srcs[j] * 16 + c];
    out2[n * 16 + c] = dinv[n] * ((a0 + a1) + (a2 + a3));
}

// one block per graph; batch sorted -> binary search the node range,
// block-reduce sums, mean + b2, log_softmax straight to d_out.
__global__ __launch_bounds__(256) void k_pool(const float* __restrict__ out2,
                                              const float* __restrict__ b2,
                                              const int* __restrict__ batch,
                                              float* __restrict__ out) {
    __shared__ float red[N_CLASSES][256];
    int g = blockIdx.x, tid = threadIdx.x;
    int lo = 0, hi = N_NODES;
    while (lo < hi) { int m = (lo + hi) >> 1; if (batch[m] < g) lo = m + 1; else hi = m; }
    int start = lo;
    lo = 0; hi = N_NODES;
    while (lo < hi) { int m = (lo + hi) >> 1; if (batch[m] < g + 1) lo = m + 1; else hi = m; }
    int end = lo;

    float sum[N_CLASSES];
#pragma unroll
    for (int j = 0; j < N_CLASSES; ++j) sum[j] = 0.f;
    for (int i = start + tid; i < end; i += 256) {
        const float* r = &out2[(long long)i * 16];
#pragma unroll
        for (int j = 0; j < N_CLASSES; ++j) sum[j] += r[j];
    }
#pragma unroll
    for (int j = 0; j < N_CLASSES; ++j) red[j][tid] = sum[j];
    __syncthreads();
    for (int s = 128; s > 0; s >>= 1) {
        if (tid < s) {
#pragma unroll
            for (int j = 0; j < N_CLASSES; ++j) red[j][tid] += red[j][tid + s];
        }
        __syncthreads();
    }
    if (tid == 0) {
        int cnt = end - start;
        float v[N_CLASSES];
        if (cnt > 0) {
            float inv = 1.f / (float)cnt;
#pragma unroll
            for (int j = 0; j < N_CLASSES; ++j) v[j] = red[j][0] * inv + b2[j];
        } else {
#pragma unroll
            for (int j = 0; j < N_CLASSES; ++j) v[j] = 0.f;
        }
        float m = v[0];
#pragma unroll
        for (int j = 1; j < N_CLASSES; ++j) m = fmaxf(m, v[j]);
        float l = 0.f;
#pragma unroll
        for (int j = 0; j < N_CLASSES; ++j) l += expf(v[j] - m);
        l = logf(l);
#pragma unroll
        for (int j = 0; j < N_CLASSES; ++j) out[g * N_CLASSES + j] = v[j] - m - l;
    }
}

extern "C" void kernel_launch(void* const* d_in, const int* in_sizes, int n_in,
                              void* d_out, int out_size, void* d_ws, size_t ws_size,
                              hipStream_t stream) {
    const float* x     = (const float*)d_in[0];
    const int*   edge  = (const int*)d_in[1];   // [2, E]
    const int*   batch = (const int*)d_in[2];
    const float* W1    = (const float*)d_in[3];
    const float* b1    = (const float*)d_in[4];
    const float* W2    = (const float*)d_in[5];
    const float* b2    = (const float*)d_in[6];
    float* out = (float*)d_out;
    float* ws  = (float*)d_ws;

    int*   gcur  = (int*)ws;                  // [0, 512)
    int*   bbase = (int*)(ws + 512);          // [512, 1024)
    float* dinv  = ws + 1024;                 // [1024, 101024)
    int*   off   = (int*)(ws + 101024);       // 100001 used
    int*   srcs  = (int*)(ws + 201056);       // 3.2M
    int*   stage = (int*)(ws + 3401056);      // 391*9216
    float* h1p   = ws + 3401056;              // overlays stage (dead after k_binB)
    float* h2p   = ws + 5001056;
    float* out2  = h1p;                       // h1p dead after k_agg1

    const int* srcp = edge;
    const int* dstp = edge + N_EDGES;

    k_ginit<<<1, 512, 0, stream>>>(gcur);
    k_binA<<<BINA_BLOCKS, 256, 0, stream>>>(srcp, dstp, gcur, stage);
    k_bscan<<<1, 512, 0, stream>>>(gcur, bbase, off);
    k_binB<<<NBUCK, 256, 0, stream>>>(gcur, bbase, stage, off, dinv, srcs);
    k_gemm1<<<N_NODES / 16, 256, 0, stream>>>(x, W1, dinv, h1p);
    k_agg1<<<N_NODES / 16, 256, 0, stream>>>(off, srcs, dinv, h1p, b1, W2, h2p);
    k_agg2<<<N_NODES / 16, 256, 0, stream>>>(off, srcs, dinv, h2p, out2);
    k_pool<<<N_GRAPHS, 256, 0, stream>>>(out2, b2, batch, out);
}